// Round 9
// baseline (267.204 us; speedup 1.0000x reference)
//
#include <hip/hip_runtime.h>
#include <stdint.h>

#define BB 32
#define AA 8400
#define CC 80
#define MM 64
#define KTOP 13
#define FEPS 1e-9f
#define CAND_CAP 1024     // worst-case in-box anchors: Binom(8400, ~0.1) mean 820, sd 27
#define CNT_STRIDE 16     // pad counters to separate cache lines
#define PLIST_CAP (BB * MM * KTOP)   // 26624 max positives

typedef unsigned long long u64;

__device__ __forceinline__ float iou_fn(float gx1, float gy1, float gx2, float gy2,
                                        float px1, float py1, float px2, float py2) {
    float ix1 = fmaxf(gx1, px1), iy1 = fmaxf(gy1, py1);
    float ix2 = fminf(gx2, px2), iy2 = fminf(gy2, py2);
    float ov = fmaxf(ix2 - ix1, 0.0f) * fmaxf(iy2 - iy1, 0.0f);
    float a1 = fmaxf(gx2 - gx1, 0.0f) * fmaxf(gy2 - gy1, 0.0f);
    float a2 = fmaxf(px2 - px1, 0.0f) * fmaxf(py2 - py1, 0.0f);
    return ov / (a1 + a2 - ov + FEPS);
}

// Kernel A: one thread per (b, anchor). Zeroes its mask64 word (consumed only
// by the NEXT node - dispatch boundary orders it). Dense 64-GT in-box test,
// then sparse metric+push (~1.7/anchor) of u64 keys (met_bits<<32 | AA-a)
// into per-(b,m) lists; u64 max == (higher met, lower index) == JAX tie order.
__global__ __launch_bounds__(256) void pairgen_kernel(
    const float* __restrict__ pred_scores, const float* __restrict__ pred_bboxes,
    const float* __restrict__ anchors, const int* __restrict__ gt_labels,
    const float* __restrict__ gt_bboxes, const float* __restrict__ pad_mask,
    int* __restrict__ cnt, u64* __restrict__ cand, u64* __restrict__ mask64)
{
    __shared__ float4 gtb_s[MM];
    __shared__ int    gtl_s[MM];
    __shared__ u64    valid_s;
    int b = blockIdx.y;
    int t = threadIdx.x;
    if (t < MM) {
        gtb_s[t] = ((const float4*)gt_bboxes)[b * MM + t];
        gtl_s[t] = gt_labels[b * MM + t];
        bool v = pad_mask[b * MM + t] != 0.0f;
        u64 bal = __ballot(v);              // wave 0 covers exactly t=0..63
        if (t == 0) valid_s = bal;
    }
    __syncthreads();
    int a = blockIdx.x * 256 + t;
    if (a >= AA) return;
    mask64[(size_t)b * AA + a] = 0ull;      // fused zero-init (next-node consumer)
    float2 xy = *(const float2*)(anchors + a * 2);
    float4 p = ((const float4*)pred_bboxes)[(size_t)b * AA + a];
    const float4* gg = (const float4*)gt_bboxes + b * MM;   // uniform loads
    u64 mask = 0;
    #pragma unroll 8
    for (int m = 0; m < MM; ++m) {
        float4 g = gg[m];
        float d = fminf(fminf(xy.x - g.x, xy.y - g.y), fminf(g.z - xy.x, g.w - xy.y));
        mask |= ((u64)(d > FEPS)) << m;
    }
    mask &= valid_s;
    if (!mask) return;
    float parea = (p.z - p.x) * (p.w - p.y);
    const float* psa = pred_scores + ((size_t)b * AA + a) * CC;
    unsigned ia = (unsigned)(AA - a);
    while (mask) {
        int m = __ffsll(mask) - 1;
        mask &= mask - 1;
        float4 g = gtb_s[m];
        float ix1 = fmaxf(g.x, p.x), iy1 = fmaxf(g.y, p.y);
        float ix2 = fminf(g.z, p.z), iy2 = fminf(g.w, p.w);
        float ov = fmaxf(ix2 - ix1, 0.0f) * fmaxf(iy2 - iy1, 0.0f);
        float garea = (g.z - g.x) * (g.w - g.y);
        float iou = ov / (garea + parea - ov + FEPS);
        float s = psa[gtl_s[m]];
        float i2 = iou * iou;
        float met = s * (i2 * i2 * i2);
        if (met > 0.0f) {
            int bm = b * MM + m;
            int slot = atomicAdd(&cnt[bm * CNT_STRIDE], 1);
            if (slot < CAND_CAP)
                cand[(size_t)bm * CAND_CAP + slot] =
                    ((u64)__float_as_uint(met) << 32) | ia;
        }
    }
}

// Kernel B: per (b,m) block. <=1024 candidates in 4 u64 regs/thread, 13 rounds
// of block u64-max (unique keys: winner cleared by equality), scatter bit into
// per-anchor 64-bit mask. atomicAdd list order is nondeterministic but max is
// order-invariant -> deterministic output.
__global__ __launch_bounds__(256) void select_scatter_kernel(
    const int* __restrict__ cnt, const u64* __restrict__ cand,
    u64* __restrict__ mask64)
{
    int bm = blockIdx.x;
    int n = min(cnt[bm * CNT_STRIDE], CAND_CAP);
    int rounds = min(n, KTOP);
    if (rounds == 0) return;
    int b = bm >> 6, m = bm & 63;
    int t = threadIdx.x;
    __shared__ u64 rv[2][4];
    u64 c[4];
    #pragma unroll
    for (int j = 0; j < 4; ++j) {
        int i = t + j * 256;
        c[j] = (i < n) ? cand[(size_t)bm * CAND_CAP + i] : 0;
    }
    int lane = t & 63, wv = t >> 6;
    for (int k = 0; k < rounds; ++k) {
        u64 bk = c[0];
        #pragma unroll
        for (int j = 1; j < 4; ++j) bk = (c[j] > bk) ? c[j] : bk;
        #pragma unroll
        for (int off = 32; off > 0; off >>= 1) {
            u64 ok = __shfl_xor(bk, off);
            bk = (ok > bk) ? ok : bk;
        }
        if (lane == 0) rv[k & 1][wv] = bk;
        __syncthreads();
        u64 wk = rv[k & 1][0];
        #pragma unroll
        for (int w = 1; w < 4; ++w) wk = (rv[k & 1][w] > wk) ? rv[k & 1][w] : wk;
        #pragma unroll
        for (int j = 0; j < 4; ++j) if (c[j] == wk) c[j] = 0;
        if (t == 0) {
            int a = AA - (int)(wk & 0xffffffffULL);
            atomicOr(&mask64[(size_t)b * AA + a], 1ull << m);
        }
    }
}

// Kernel C: per anchor — resolve multi-assignment (first-argmax IoU over ALL m
// incl. padded, as reference), write labels/bboxes, per-GT atomicMax
// align/iou, append positives to compact list. The 80-wide score zeroing is
// done BLOCK-COOPERATIVELY over the block's contiguous 80KB slab so that
// consecutive lanes write consecutive float4s (coalesced, vs 320B-strided
// per-thread rows which ran at 1.7 TB/s in R8).
__global__ __launch_bounds__(256) void resolve_kernel(
    const float* __restrict__ pred_scores, const float* __restrict__ pred_bboxes,
    const int* __restrict__ gt_labels, const float* __restrict__ gt_bboxes,
    const int* __restrict__ bg_ptr,
    const u64* __restrict__ mask64,
    float* __restrict__ out_labels, float* __restrict__ out_bboxes,
    float* __restrict__ out_scores,
    float* __restrict__ assigned_align,
    unsigned int* __restrict__ maxmet, unsigned int* __restrict__ maxiou,
    int* __restrict__ pcnt, int2* __restrict__ plist)
{
    __shared__ float4 gtb_s[MM];
    __shared__ int    gtl_s[MM];
    int b = blockIdx.y;
    int t = threadIdx.x;
    if (t < MM) {
        gtb_s[t] = ((const float4*)gt_bboxes)[b * MM + t];
        gtl_s[t] = gt_labels[b * MM + t];
    }
    __syncthreads();

    // Coalesced zero of this block's score slab: anchors [a0, a0+na)
    {
        int a0 = blockIdx.x * 256;
        int na = min(256, AA - a0);
        float4* slab = (float4*)(out_scores + ((size_t)b * AA + a0) * CC);
        int total = na * (CC / 4);
        float4 z = make_float4(0.0f, 0.0f, 0.0f, 0.0f);
        for (int i = t; i < total; i += 256) slab[i] = z;
    }

    int a = blockIdx.x * 256 + t;
    if (a >= AA) return;
    size_t ga = (size_t)b * AA + a;
    u64 mask = mask64[ga];
    int pc = __popcll(mask);
    float4 p = ((const float4*)pred_bboxes)[ga];
    int mstar = -1;
    if (pc == 1) {
        mstar = __ffsll(mask) - 1;
    } else if (pc > 1) {
        float best = -1.0f; int bi = 0;
        for (int m = 0; m < MM; ++m) {
            float4 g = gtb_s[m];
            float iou = iou_fn(g.x, g.y, g.z, g.w, p.x, p.y, p.z, p.w);
            if (iou > best) { best = iou; bi = m; }   // strict >: first occurrence
        }
        mstar = bi;
    }
    int bidx = (mstar >= 0) ? mstar : 0;   // argmax of all-zero column = 0
    float4 g = gtb_s[bidx];
    ((float4*)out_bboxes)[ga] = g;
    out_labels[ga] = (mstar >= 0) ? (float)gtl_s[mstar] : (float)(*bg_ptr);
    if (mstar >= 0) {
        float iou = iou_fn(g.x, g.y, g.z, g.w, p.x, p.y, p.z, p.w);
        float s = pred_scores[ga * CC + gtl_s[mstar]];
        float i2 = iou * iou;
        float al = s * (i2 * i2 * i2);
        assigned_align[ga] = al;
        atomicMax(&maxmet[b * MM + mstar], __float_as_uint(al));
        atomicMax(&maxiou[b * MM + mstar], __float_as_uint(iou));
        int idx = atomicAdd(pcnt, 1);
        plist[idx] = make_int2((int)ga, mstar);
    }
}

// Kernel D: fixup — one thread per positive anchor (~9k), write its single
// scale float into the already-zeroed score row.
__global__ __launch_bounds__(256) void fixup_kernel(
    const int* __restrict__ gt_labels,
    const int* __restrict__ pcnt, const int2* __restrict__ plist,
    const float* __restrict__ assigned_align,
    const unsigned int* __restrict__ maxmet, const unsigned int* __restrict__ maxiou,
    float* __restrict__ out_scores)
{
    int i = blockIdx.x * blockDim.x + threadIdx.x;
    if (i >= *pcnt) return;
    int2 e = plist[i];
    size_t ga = (size_t)e.x;
    int m = e.y;
    int b = (int)(ga / AA);
    int label = gt_labels[b * MM + m];
    float mm = __uint_as_float(maxmet[b * MM + m]);
    float mi = __uint_as_float(maxiou[b * MM + m]);
    float scale = assigned_align[ga] / (mm + FEPS) * mi;
    out_scores[ga * CC + label] = scale;
}

extern "C" void kernel_launch(void* const* d_in, const int* in_sizes, int n_in,
                              void* d_out, int out_size, void* d_ws, size_t ws_size,
                              hipStream_t stream) {
    const float* pred_scores = (const float*)d_in[0];
    const float* pred_bboxes = (const float*)d_in[1];
    const float* anchors     = (const float*)d_in[2];
    const int*   gt_labels   = (const int*)d_in[3];
    const float* gt_bboxes   = (const float*)d_in[4];
    const float* pad_mask    = (const float*)d_in[5];
    const int*   bg_ptr      = (const int*)d_in[6];

    // Workspace (~21 MB). Zeroed prefix (contiguous, small): cnt + maxmet +
    // maxiou + pcnt. mask64 is zeroed inside pairgen.
    char* ws = (char*)d_ws;
    size_t off = 0;
    int* cnt = (int*)(ws + off);
    off += (size_t)BB * MM * CNT_STRIDE * sizeof(int);
    unsigned int* maxmet = (unsigned int*)(ws + off);
    off += (size_t)BB * MM * sizeof(unsigned int);
    unsigned int* maxiou = (unsigned int*)(ws + off);
    off += (size_t)BB * MM * sizeof(unsigned int);
    int* pcnt = (int*)(ws + off);
    off += 16;
    size_t zero_bytes = off;
    u64* mask64 = (u64*)(ws + off);
    off += (size_t)BB * AA * sizeof(u64);
    u64* cand = (u64*)(ws + off);
    off += (size_t)BB * MM * CAND_CAP * sizeof(u64);
    float* assigned_align = (float*)(ws + off);
    off += (size_t)BB * AA * sizeof(float);
    int2* plist = (int2*)(ws + off);
    off += (size_t)PLIST_CAP * sizeof(int2);

    hipMemsetAsync(ws, 0, zero_bytes, stream);

    float* out = (float*)d_out;
    float* out_labels = out;                         // B*A
    float* out_bboxes = out + (size_t)BB * AA;       // B*A*4
    float* out_scores = out + (size_t)BB * AA * 5;   // B*A*80

    dim3 gridA((AA + 255) / 256, BB);
    pairgen_kernel<<<gridA, 256, 0, stream>>>(
        pred_scores, pred_bboxes, anchors, gt_labels, gt_bboxes, pad_mask,
        cnt, cand, mask64);

    select_scatter_kernel<<<BB * MM, 256, 0, stream>>>(cnt, cand, mask64);

    resolve_kernel<<<gridA, 256, 0, stream>>>(
        pred_scores, pred_bboxes, gt_labels, gt_bboxes, bg_ptr, mask64,
        out_labels, out_bboxes, out_scores, assigned_align,
        maxmet, maxiou, pcnt, plist);

    fixup_kernel<<<(PLIST_CAP + 255) / 256, 256, 0, stream>>>(
        gt_labels, pcnt, plist, assigned_align, maxmet, maxiou, out_scores);
}

// Round 10
// 238.093 us; speedup vs baseline: 1.1223x; 1.1223x over previous
//
#include <hip/hip_runtime.h>
#include <stdint.h>

#define BB 32
#define AA 8400
#define CC 80
#define MM 64
#define KTOP 13
#define FEPS 1e-9f
#define CAND_CAP 1024     // worst-case in-box anchors: Binom(8400, ~0.1) mean 820, sd 27
#define CNT_STRIDE 16     // pad counters to separate cache lines
#define PLIST_CAP (BB * MM * KTOP)   // 26624 max positives

typedef unsigned long long u64;

__device__ __forceinline__ float iou_fn(float gx1, float gy1, float gx2, float gy2,
                                        float px1, float py1, float px2, float py2) {
    float ix1 = fmaxf(gx1, px1), iy1 = fmaxf(gy1, py1);
    float ix2 = fminf(gx2, px2), iy2 = fminf(gy2, py2);
    float ov = fmaxf(ix2 - ix1, 0.0f) * fmaxf(iy2 - iy1, 0.0f);
    float a1 = fmaxf(gx2 - gx1, 0.0f) * fmaxf(gy2 - gy1, 0.0f);
    float a2 = fmaxf(px2 - px1, 0.0f) * fmaxf(py2 - py1, 0.0f);
    return ov / (a1 + a2 - ov + FEPS);
}

// Kernel A: one thread per (b, anchor). Zeroes its mask64 word (consumed only
// by the NEXT node - dispatch boundary orders it). Dense 64-GT in-box test,
// then sparse metric+push (~1.7/anchor) of u64 keys (met_bits<<32 | AA-a)
// into per-(b,m) lists; u64 max == (higher met, lower index) == JAX tie order.
__global__ __launch_bounds__(256) void pairgen_kernel(
    const float* __restrict__ pred_scores, const float* __restrict__ pred_bboxes,
    const float* __restrict__ anchors, const int* __restrict__ gt_labels,
    const float* __restrict__ gt_bboxes, const float* __restrict__ pad_mask,
    int* __restrict__ cnt, u64* __restrict__ cand, u64* __restrict__ mask64)
{
    __shared__ float4 gtb_s[MM];
    __shared__ int    gtl_s[MM];
    __shared__ u64    valid_s;
    int b = blockIdx.y;
    int t = threadIdx.x;
    if (t < MM) {
        gtb_s[t] = ((const float4*)gt_bboxes)[b * MM + t];
        gtl_s[t] = gt_labels[b * MM + t];
        bool v = pad_mask[b * MM + t] != 0.0f;
        u64 bal = __ballot(v);              // wave 0 covers exactly t=0..63
        if (t == 0) valid_s = bal;
    }
    __syncthreads();
    int a = blockIdx.x * 256 + t;
    if (a >= AA) return;
    mask64[(size_t)b * AA + a] = 0ull;      // fused zero-init (next-node consumer)
    float2 xy = *(const float2*)(anchors + a * 2);
    float4 p = ((const float4*)pred_bboxes)[(size_t)b * AA + a];
    const float4* gg = (const float4*)gt_bboxes + b * MM;   // uniform loads
    u64 mask = 0;
    #pragma unroll 8
    for (int m = 0; m < MM; ++m) {
        float4 g = gg[m];
        float d = fminf(fminf(xy.x - g.x, xy.y - g.y), fminf(g.z - xy.x, g.w - xy.y));
        mask |= ((u64)(d > FEPS)) << m;
    }
    mask &= valid_s;
    if (!mask) return;
    float parea = (p.z - p.x) * (p.w - p.y);
    const float* psa = pred_scores + ((size_t)b * AA + a) * CC;
    unsigned ia = (unsigned)(AA - a);
    while (mask) {
        int m = __ffsll(mask) - 1;
        mask &= mask - 1;
        float4 g = gtb_s[m];
        float ix1 = fmaxf(g.x, p.x), iy1 = fmaxf(g.y, p.y);
        float ix2 = fminf(g.z, p.z), iy2 = fminf(g.w, p.w);
        float ov = fmaxf(ix2 - ix1, 0.0f) * fmaxf(iy2 - iy1, 0.0f);
        float garea = (g.z - g.x) * (g.w - g.y);
        float iou = ov / (garea + parea - ov + FEPS);
        float s = psa[gtl_s[m]];
        float i2 = iou * iou;
        float met = s * (i2 * i2 * i2);
        if (met > 0.0f) {
            int bm = b * MM + m;
            int slot = atomicAdd(&cnt[bm * CNT_STRIDE], 1);
            if (slot < CAND_CAP)
                cand[(size_t)bm * CAND_CAP + slot] =
                    ((u64)__float_as_uint(met) << 32) | ia;
        }
    }
}

// Kernel B: per (b,m) block. <=1024 candidates in 4 u64 regs/thread, 13 rounds
// of block u64-max (unique keys: winner cleared by equality), scatter bit into
// per-anchor 64-bit mask. atomicAdd list order is nondeterministic but max is
// order-invariant -> deterministic output.
__global__ __launch_bounds__(256) void select_scatter_kernel(
    const int* __restrict__ cnt, const u64* __restrict__ cand,
    u64* __restrict__ mask64)
{
    int bm = blockIdx.x;
    int n = min(cnt[bm * CNT_STRIDE], CAND_CAP);
    int rounds = min(n, KTOP);
    if (rounds == 0) return;
    int b = bm >> 6, m = bm & 63;
    int t = threadIdx.x;
    __shared__ u64 rv[2][4];
    u64 c[4];
    #pragma unroll
    for (int j = 0; j < 4; ++j) {
        int i = t + j * 256;
        c[j] = (i < n) ? cand[(size_t)bm * CAND_CAP + i] : 0;
    }
    int lane = t & 63, wv = t >> 6;
    for (int k = 0; k < rounds; ++k) {
        u64 bk = c[0];
        #pragma unroll
        for (int j = 1; j < 4; ++j) bk = (c[j] > bk) ? c[j] : bk;
        #pragma unroll
        for (int off = 32; off > 0; off >>= 1) {
            u64 ok = __shfl_xor(bk, off);
            bk = (ok > bk) ? ok : bk;
        }
        if (lane == 0) rv[k & 1][wv] = bk;
        __syncthreads();
        u64 wk = rv[k & 1][0];
        #pragma unroll
        for (int w = 1; w < 4; ++w) wk = (rv[k & 1][w] > wk) ? rv[k & 1][w] : wk;
        #pragma unroll
        for (int j = 0; j < 4; ++j) if (c[j] == wk) c[j] = 0;
        if (t == 0) {
            int a = AA - (int)(wk & 0xffffffffULL);
            atomicOr(&mask64[(size_t)b * AA + a], 1ull << m);
        }
    }
}

// Kernel C: per anchor — resolve multi-assignment (first-argmax IoU over ALL m
// incl. padded, as reference), write labels/bboxes, per-GT atomicMax
// align/iou, append positives to compact list (per-block LDS aggregation ->
// ONE global atomicAdd per block instead of one per positive anchor).
// out_scores zeroing is delegated to hipMemsetAsync (AMD's fill kernel runs
// at 6.5 TB/s; this kernel's store issue rate plateaued at ~1.5 TB/s in R8/R9).
__global__ __launch_bounds__(256) void resolve_kernel(
    const float* __restrict__ pred_scores, const float* __restrict__ pred_bboxes,
    const int* __restrict__ gt_labels, const float* __restrict__ gt_bboxes,
    const int* __restrict__ bg_ptr,
    const u64* __restrict__ mask64,
    float* __restrict__ out_labels, float* __restrict__ out_bboxes,
    float* __restrict__ assigned_align,
    unsigned int* __restrict__ maxmet, unsigned int* __restrict__ maxiou,
    int* __restrict__ pcnt, int2* __restrict__ plist)
{
    __shared__ float4 gtb_s[MM];
    __shared__ int    gtl_s[MM];
    __shared__ int    lcnt, lbase;
    int b = blockIdx.y;
    int t = threadIdx.x;
    if (t == 0) lcnt = 0;
    if (t < MM) {
        gtb_s[t] = ((const float4*)gt_bboxes)[b * MM + t];
        gtl_s[t] = gt_labels[b * MM + t];
    }
    __syncthreads();
    int a = blockIdx.x * 256 + t;
    bool active = (a < AA);
    int mstar = -1, myslot = -1;
    size_t ga = 0;
    if (active) {
        ga = (size_t)b * AA + a;
        u64 mask = mask64[ga];
        int pc = __popcll(mask);
        float4 p = ((const float4*)pred_bboxes)[ga];
        if (pc == 1) {
            mstar = __ffsll(mask) - 1;
        } else if (pc > 1) {
            float best = -1.0f; int bi = 0;
            for (int m = 0; m < MM; ++m) {
                float4 g = gtb_s[m];
                float iou = iou_fn(g.x, g.y, g.z, g.w, p.x, p.y, p.z, p.w);
                if (iou > best) { best = iou; bi = m; }   // strict >: first occurrence
            }
            mstar = bi;
        }
        int bidx = (mstar >= 0) ? mstar : 0;   // argmax of all-zero column = 0
        float4 g = gtb_s[bidx];
        ((float4*)out_bboxes)[ga] = g;
        out_labels[ga] = (mstar >= 0) ? (float)gtl_s[mstar] : (float)(*bg_ptr);
        if (mstar >= 0) {
            float iou = iou_fn(g.x, g.y, g.z, g.w, p.x, p.y, p.z, p.w);
            float s = pred_scores[ga * CC + gtl_s[mstar]];
            float i2 = iou * iou;
            float al = s * (i2 * i2 * i2);
            assigned_align[ga] = al;
            atomicMax(&maxmet[b * MM + mstar], __float_as_uint(al));
            atomicMax(&maxiou[b * MM + mstar], __float_as_uint(iou));
            myslot = atomicAdd(&lcnt, 1);      // LDS atomic: fast
        }
    }
    __syncthreads();
    if (t == 0 && lcnt > 0) lbase = atomicAdd(pcnt, lcnt);
    __syncthreads();
    if (myslot >= 0) plist[lbase + myslot] = make_int2((int)ga, mstar);
}

// Kernel D: fixup — one thread per positive anchor (~9k), write its single
// scale float into the memset-zeroed score plane.
__global__ __launch_bounds__(256) void fixup_kernel(
    const int* __restrict__ gt_labels,
    const int* __restrict__ pcnt, const int2* __restrict__ plist,
    const float* __restrict__ assigned_align,
    const unsigned int* __restrict__ maxmet, const unsigned int* __restrict__ maxiou,
    float* __restrict__ out_scores)
{
    int i = blockIdx.x * blockDim.x + threadIdx.x;
    if (i >= *pcnt) return;
    int2 e = plist[i];
    size_t ga = (size_t)e.x;
    int m = e.y;
    int b = (int)(ga / AA);
    int label = gt_labels[b * MM + m];
    float mm = __uint_as_float(maxmet[b * MM + m]);
    float mi = __uint_as_float(maxiou[b * MM + m]);
    float scale = assigned_align[ga] / (mm + FEPS) * mi;
    out_scores[ga * CC + label] = scale;
}

extern "C" void kernel_launch(void* const* d_in, const int* in_sizes, int n_in,
                              void* d_out, int out_size, void* d_ws, size_t ws_size,
                              hipStream_t stream) {
    const float* pred_scores = (const float*)d_in[0];
    const float* pred_bboxes = (const float*)d_in[1];
    const float* anchors     = (const float*)d_in[2];
    const int*   gt_labels   = (const int*)d_in[3];
    const float* gt_bboxes   = (const float*)d_in[4];
    const float* pad_mask    = (const float*)d_in[5];
    const int*   bg_ptr      = (const int*)d_in[6];

    // Workspace (~21 MB). Zeroed prefix (contiguous, small): cnt + maxmet +
    // maxiou + pcnt. mask64 is zeroed inside pairgen.
    char* ws = (char*)d_ws;
    size_t off = 0;
    int* cnt = (int*)(ws + off);
    off += (size_t)BB * MM * CNT_STRIDE * sizeof(int);
    unsigned int* maxmet = (unsigned int*)(ws + off);
    off += (size_t)BB * MM * sizeof(unsigned int);
    unsigned int* maxiou = (unsigned int*)(ws + off);
    off += (size_t)BB * MM * sizeof(unsigned int);
    int* pcnt = (int*)(ws + off);
    off += 16;
    size_t zero_bytes = off;
    u64* mask64 = (u64*)(ws + off);
    off += (size_t)BB * AA * sizeof(u64);
    u64* cand = (u64*)(ws + off);
    off += (size_t)BB * MM * CAND_CAP * sizeof(u64);
    float* assigned_align = (float*)(ws + off);
    off += (size_t)BB * AA * sizeof(float);
    int2* plist = (int2*)(ws + off);
    off += (size_t)PLIST_CAP * sizeof(int2);

    hipMemsetAsync(ws, 0, zero_bytes, stream);

    float* out = (float*)d_out;
    float* out_labels = out;                         // B*A
    float* out_bboxes = out + (size_t)BB * AA;       // B*A*4
    float* out_scores = out + (size_t)BB * AA * 5;   // B*A*80

    // 86 MB score plane: AMD's fill kernel sustains ~6.5 TB/s (measured R6),
    // 4x what our compute kernels reached issuing the same stores.
    hipMemsetAsync(out_scores, 0, (size_t)BB * AA * CC * sizeof(float), stream);

    dim3 gridA((AA + 255) / 256, BB);
    pairgen_kernel<<<gridA, 256, 0, stream>>>(
        pred_scores, pred_bboxes, anchors, gt_labels, gt_bboxes, pad_mask,
        cnt, cand, mask64);

    select_scatter_kernel<<<BB * MM, 256, 0, stream>>>(cnt, cand, mask64);

    resolve_kernel<<<gridA, 256, 0, stream>>>(
        pred_scores, pred_bboxes, gt_labels, gt_bboxes, bg_ptr, mask64,
        out_labels, out_bboxes, assigned_align, maxmet, maxiou, pcnt, plist);

    fixup_kernel<<<(PLIST_CAP + 255) / 256, 256, 0, stream>>>(
        gt_labels, pcnt, plist, assigned_align, maxmet, maxiou, out_scores);
}